// Round 3
// 417.686 us; speedup vs baseline: 1.0112x; 1.0112x over previous
//
#include <hip/hip_runtime.h>

// ---------------------------------------------------------------------------
// BNN MC forward: 150 weight samples of a 784->512->512->512->10 MLP, batch 64.
// Reproduces jax.random (threefry2x32, partitionable=True) exactly (to well
// within the harness absmax threshold).
// R14 = R13 with the real bug fixed + packed-FP32 restored.
// Bug history: R12/R13 failed with IDENTICAL absmax 10.1467 -> deterministic,
// shared-change bug. Root cause: "2.99999994f" literal rounds to 3.0f
// (ulp(3)=2^-22), so x = 2m-1 EXACTLY; m=0 (p=2^-23, ~7.6 hits/layer) gives
// x=-1 -> log2(0) = -inf -> inf/NaN weights -> relu-squashed finite error.
// Fix: verbatim R11 x-formation (f = u-1.0f; x = fma(f,2,-0.99999994f)),
// mantissa build via v_alignbit (exact). The identical-error bisect also
// EXONERATES v_pk_fma_f32/v_pk_mul_f32 (R13 removed them, error unchanged),
// so packed poly/t/px/wv are restored.
// Retained from R12/R13 (all re-verified bit-exact):
//   1) threefry init merged into round 1; key injections merged with the
//      next round's add (v_add3).
//   2) v_cvt_pk_bf16_f32 inline asm (HW-verified, learn_hip m214v22).
//   3) pack layout (mu,mu,sg,sg) per 16B -> packed wv fma.
//   4) L0 K-pad 832 -> 800 (last K-step was entirely zero-weight).
// ws usage ~25.0 MB (hB aliases msP0).
// ---------------------------------------------------------------------------

typedef short bf16x8 __attribute__((ext_vector_type(8)));
typedef int   i32x4  __attribute__((ext_vector_type(4)));
typedef float f32x4  __attribute__((ext_vector_type(4)));
typedef float f32x2  __attribute__((ext_vector_type(2)));

__device__ __forceinline__ f32x2 mk2(float a, float b)
{
  f32x2 r; r.x = a; r.y = b; return r;
}

// packed FP32 (VOP3P): two IEEE fma/mul per issue slot. Exonerated by the
// R12==R13 identical-absmax bisect (default op_sel_hi is correct).
__device__ __forceinline__ f32x2 pk_fma(f32x2 a, f32x2 b, f32x2 c)
{
  f32x2 d;
  asm("v_pk_fma_f32 %0, %1, %2, %3" : "=v"(d) : "v"(a), "v"(b), "v"(c));
  return d;
}
__device__ __forceinline__ f32x2 pk_mul(f32x2 a, f32x2 b)
{
  f32x2 d;
  asm("v_pk_mul_f32 %0, %1, %2" : "=v"(d) : "v"(a), "v"(b));
  return d;
}

// a -> low 16, b -> high 16, RNE (== manual RNE trick for all finite inputs).
// HW-verified on gfx950 (learn_hip m214v22).
__device__ __forceinline__ unsigned int cvt_pk_bf16(float a, float b)
{
  unsigned int d;
  asm("v_cvt_pk_bf16_f32 %0, %1, %2" : "=v"(d) : "v"(a), "v"(b));
  return d;
}

#define TF_R(r) { x0 += x1; x1 = (x1 << (r)) | (x1 >> (32 - (r))); x1 ^= x0; }

// 8-chain round-major threefry pieces (a[8], b[8] in scope)
#define TF8(r) { _Pragma("unroll") for (int j = 0; j < 8; ++j) { \
    a[j] += b[j]; b[j] = (b[j] << (r)) | (b[j] >> (32 - (r))); b[j] ^= a[j]; } }
// rot+xor only (the preceding a+=b has been absorbed elsewhere)
#define ROTX8(r) { _Pragma("unroll") for (int j = 0; j < 8; ++j) { \
    b[j] = ((b[j] << (r)) | (b[j] >> (32 - (r)))) ^ a[j]; } }
// key injection merged with the NEXT round's a+=b:  b += kkb; a = a + b + kka
// (associativity mod 2^32 -> bit-exact; compiles to v_add + v_add3)
#define INJM8(kka, kkb) { const unsigned int _ka = (kka), _kb = (kkb); \
    _Pragma("unroll") for (int j = 0; j < 8; ++j) { \
    b[j] += _kb; a[j] = a[j] + b[j] + _ka; } }

// full merged 20-round threefry on the 8 chains; needs a[],b[],cb,k0,k1,ks2
// in scope; leaves out[j] = x0^x1 in rout[]. Verified chain-equal to the
// R11 round sequence (symbolic trace, 3x).
#define TF8_FULL(rout) { \
    const unsigned int _kc = cb + k0; \
    _Pragma("unroll") for (int j = 0; j < 8; ++j) { \
      b[j] = cb + (unsigned int)j; a[j] = _kc + (unsigned int)j; } \
    ROTX8(13) TF8(15) TF8(26) TF8(6) \
    INJM8(k1, ks2 + 1u)  ROTX8(17) TF8(29) TF8(16) TF8(24) \
    INJM8(ks2, k0 + 2u)  ROTX8(13) TF8(15) TF8(26) TF8(6) \
    INJM8(k0, k1 + 3u)   ROTX8(17) TF8(29) TF8(16) TF8(24) \
    INJM8(k1, ks2 + 4u)  ROTX8(13) TF8(15) TF8(26) TF8(6) \
    const unsigned int _f1 = k0 + 5u; \
    _Pragma("unroll") for (int j = 0; j < 8; ++j) \
      rout[j] = (a[j] + ks2) ^ (b[j] + _f1); }

// Threefry-2x32, counter (0, c1), returns x0^x1 — scalar version (bias kernel)
__device__ __forceinline__ unsigned int tf_xor(unsigned int k0, unsigned int k1,
                                               unsigned int c1)
{
  const unsigned int ks2 = k0 ^ k1 ^ 0x1BD11BDAu;
  unsigned int x0 = k0;          // c0 = 0 (+ ks[0])
  unsigned int x1 = c1 + k1;
  TF_R(13) TF_R(15) TF_R(26) TF_R(6)
  x0 += k1;  x1 += ks2 + 1u;
  TF_R(17) TF_R(29) TF_R(16) TF_R(24)
  x0 += ks2; x1 += k0 + 2u;
  TF_R(13) TF_R(15) TF_R(26) TF_R(6)
  x0 += k0;  x1 += k1 + 3u;
  TF_R(17) TF_R(29) TF_R(16) TF_R(24)
  x0 += k1;  x1 += ks2 + 4u;
  TF_R(13) TF_R(15) TF_R(26) TF_R(6)
  x0 += ks2; x1 += k0 + 5u;
  return x0 ^ x1;
}

// rare erfinv tail (w >= 5, p ~ 0.34%) — identical to R6..R13 selected values
__device__ __forceinline__ float erfinv_tail(float L)
{
  float w  = L * -0.6931472f;
  float t2 = sqrtf(w) - 3.0f;
  float pt = 0.00573950773f;
  pt = __builtin_fmaf(pt, t2, -0.0076224613f);
  pt = __builtin_fmaf(pt, t2, 0.00943887047f);
  pt = __builtin_fmaf(pt, t2, 1.00167406f);
  pt = __builtin_fmaf(pt, t2, 2.83297682f);
  return pt;
}

// mantissa build: (r>>9)|0x3F800000 in one v_alignbit_b32 (exact).
__device__ __forceinline__ float bits_to_f(unsigned int r)
{
  return __uint_as_float(__builtin_amdgcn_alignbit(0x7Fu, r, 9u)) - 1.0f;
}

// bits -> g where eps = sqrt(2)*g; caller folds sqrt(2) into sigma.
// x-formation is VERBATIM R11: x = fma(f, 2, -0.99999994f) — x never hits
// +-1, so log2(1-x^2) is always finite (the R12/R13 bug).
__device__ __forceinline__ float bits_to_g(unsigned int r)
{
  float f = bits_to_f(r);
  float x = __builtin_fmaf(f, 2.0f, -0.99999994f);
  float L = __log2f(__builtin_fmaf(-x, x, 1.0f));             // log2(1-x^2) <= 0
  float t  = __builtin_fmaf(L, -0.6931472f, -2.5f);
  float p = -4.39150654e-06f;
  p = __builtin_fmaf(p, t, 0.00021858087f);
  p = __builtin_fmaf(p, t, -0.00125372503f);
  p = __builtin_fmaf(p, t, -0.00417768164f);
  p = __builtin_fmaf(p, t, 0.246640727f);
  p = __builtin_fmaf(p, t, 1.50140941f);
  if (__builtin_expect(L <= -7.2134752f, 0))
    p = erfinv_tail(L);
  return p * x;
}

// paired version: packed t/poly/mul; per-half IEEE identical to scalar
// (scalar log2 and 1-x^2 keep the free neg/abs modifiers).
__device__ __forceinline__ f32x2 bits_to_g2(unsigned int r0, unsigned int r1)
{
  float f0 = bits_to_f(r0);
  float f1 = bits_to_f(r1);
  f32x2 x = pk_fma(mk2(f0, f1), mk2(2.0f, 2.0f),
                   mk2(-0.99999994f, -0.99999994f));
  float L0 = __log2f(__builtin_fmaf(-x.x, x.x, 1.0f));
  float L1 = __log2f(__builtin_fmaf(-x.y, x.y, 1.0f));
  f32x2 t = pk_fma(mk2(L0, L1), mk2(-0.6931472f, -0.6931472f),
                   mk2(-2.5f, -2.5f));
  f32x2 p = mk2(-4.39150654e-06f, -4.39150654e-06f);
  p = pk_fma(p, t, mk2(0.00021858087f, 0.00021858087f));
  p = pk_fma(p, t, mk2(-0.00125372503f, -0.00125372503f));
  p = pk_fma(p, t, mk2(-0.00417768164f, -0.00417768164f));
  p = pk_fma(p, t, mk2(0.246640727f, 0.246640727f));
  p = pk_fma(p, t, mk2(1.50140941f, 1.50140941f));
  if (__builtin_expect(L0 <= -7.2134752f, 0)) p.x = erfinv_tail(L0);
  if (__builtin_expect(L1 <= -7.2134752f, 0)) p.y = erfinv_tail(L1);
  return pk_mul(p, x);
}

__device__ __forceinline__ unsigned short f32_to_bf16_rne(float v)
{
  unsigned int u = __float_as_uint(v);
  unsigned int r = (u + 0x7FFFu + ((u >> 16) & 1u)) >> 16;   // RNE
  return (unsigned short)r;
}

// ---------------------------------------------------------------------------
// x (64,784) fp32 -> bf16, K padded 784 -> 800 with zeros
__global__ __launch_bounds__(256) void xpad_kernel(const float* __restrict__ x,
                                                   unsigned short* __restrict__ xp)
{
  int i = blockIdx.x * 256 + threadIdx.x;          // grid 200 -> 51200 == 64*800
  if (i >= 64 * 800) return;
  int m = i / 800, k = i - m * 800;
  float v = (k < 784) ? x[m * 784 + k] : 0.0f;
  xp[i] = f32_to_bf16_rne(v);
}

// ---------------------------------------------------------------------------
// Pack (mu, exp(v)*sqrt2) into [k/8][n][8] float2, zero-padded in k and n.
// Layout: each 16B group holds (mu_k, mu_{k+1}, sg_k, sg_{k+1}).
__global__ __launch_bounds__(256) void pack_kernel(
    const float* __restrict__ muW0, const float* __restrict__ vW0,
    const float* __restrict__ muW1, const float* __restrict__ vW1,
    const float* __restrict__ muW2, const float* __restrict__ vW2,
    const float* __restrict__ muW3, const float* __restrict__ vW3,
    float2* __restrict__ msP0, float2* __restrict__ msP1,
    float2* __restrict__ msP2, float2* __restrict__ msP3)
{
  int b = blockIdx.x, tid = threadIdx.x;
  const float* mu; const float* v; float2* o;
  int KV, NV, osh, base;
  if (b < 1600)      { mu = muW0; v = vW0; o = msP0; KV = 784; NV = 512; osh = 9; base = 0;    }
  else if (b < 2624) { mu = muW1; v = vW1; o = msP1; KV = 512; NV = 512; osh = 9; base = 1600; }
  else if (b < 3648) { mu = muW2; v = vW2; o = msP2; KV = 512; NV = 512; osh = 9; base = 2624; }
  else               { mu = muW3; v = vW3; o = msP3; KV = 512; NV = 10;  osh = 4; base = 3648; }
  int e = (b - base) * 256 + tid;
  int k = (e & 7) | ((e >> (3 + osh)) << 3);
  int n = (e >> 3) & ((1 << osh) - 1);
  float mu_v = 0.0f, sg_v = 0.0f;
  if (k < KV && n < NV) {
    mu_v = mu[n * KV + k];
    sg_v = __expf(v[n * KV + k]) * 1.41421356237f;
  }
  // pair (e even, e+1): same n, k and k+1 (pairs never straddle KV; KV even)
  float mu_o = __shfl_xor(mu_v, 1);
  float sg_o = __shfl_xor(sg_v, 1);
  float2 r;
  if ((e & 1) == 0) { r.x = mu_v; r.y = mu_o; }
  else              { r.x = sg_o; r.y = sg_v; }
  o[e] = r;
}

// ---------------------------------------------------------------------------
// Sample all 4 bias tensors -> fp32 in ws.  b_l[s][o] = mu[o] + exp(v[o])*eps
__global__ __launch_bounds__(256) void bias_kernel(
    const float* __restrict__ mu0, const float* __restrict__ v0, float* __restrict__ o0,
    const float* __restrict__ mu1, const float* __restrict__ v1, float* __restrict__ o1,
    const float* __restrict__ mu2, const float* __restrict__ v2, float* __restrict__ o2,
    const float* __restrict__ mu3, const float* __restrict__ v3, float* __restrict__ o3,
    unsigned int k00, unsigned int k01, unsigned int k10, unsigned int k11,
    unsigned int k20, unsigned int k21, unsigned int k30, unsigned int k31)
{
  int b = blockIdx.x, tid = threadIdx.x;
  int seg = b / 300; if (seg > 3) seg = 3;
  const float* mu; const float* v; float* o; unsigned int ka, kb; int n;
  if      (seg == 0) { mu = mu0; v = v0; o = o0; ka = k00; kb = k01; n = 76800; }
  else if (seg == 1) { mu = mu1; v = v1; o = o1; ka = k10; kb = k11; n = 76800; }
  else if (seg == 2) { mu = mu2; v = v2; o = o2; ka = k20; kb = k21; n = 76800; }
  else               { mu = mu3; v = v3; o = o3; ka = k30; kb = k31; n = 1500;  }
  int e = (b - seg * 300) * 256 + tid;
  if (e >= n) return;
  int oo = (seg == 3) ? (e % 10) : (e & 511);
  float eps = 1.41421356237f * bits_to_g(tf_xor(ka, kb, (unsigned int)e));
  o[e] = __builtin_fmaf(__expf(v[oo]), eps, mu[oo]);
}

// ---------------------------------------------------------------------------
// bias3_out: initialize d_out[s][m][n] = b3s[s][n]  (150*64*10 = 96000 f32)
__global__ __launch_bounds__(256) void bias3_out(float* __restrict__ Out,
                                                 const float* __restrict__ b3s)
{
  int i = blockIdx.x * 256 + threadIdx.x;   // grid 375
  if (i >= 96000) return;
  int s = i / 640;
  int rem = i - s * 640;
  int n = rem % 10;
  Out[i] = b3s[s * 10 + n];
}

// ---------------------------------------------------------------------------
// Fused big layer (R7 structure, grid dim3(32,150)):
//   block = 4 waves, one 16-col n-range x all 64 m x full K; K-split across
//   waves; ping-pong register prefetch pinned with sched_barrier(0);
//   LDS reduce; epilogue bias+relu, bf16 out.
// amdgpu_waves_per_eu(1,4): scheduler targets 4 waves/EU, freeing <=128 VGPR.
// mfma_f32_16x16x32_bf16: A/B frag lane holds row (lane&15), k=(lane>>4)*8+j;
// C/D lane holds col n=(lane&15), rows m=(lane>>4)*4+reg.
template<int KVALID, int KPAD, int ASTRIDE, int AROW>
__global__
__attribute__((amdgpu_flat_work_group_size(256, 256)))
__attribute__((amdgpu_waves_per_eu(1, 4)))
void layer_fused(
    const unsigned short* __restrict__ A,   // bf16 [s][64][AROW] (ASTRIDE=0: shared x)
    unsigned short* __restrict__ Out,       // bf16 [s][64][512]
    const float2* __restrict__ msP,         // [KPAD/8][512][8] (mu,mu,sg,sg pairs)
    const float* __restrict__ bS,           // [s][512]
    unsigned int k0, unsigned int k1)
{
  constexpr int NSTEPS = KPAD / 32;
  constexpr int OVALID = 512, OPITCH = 512;
  const unsigned int ks2 = k0 ^ k1 ^ 0x1BD11BDAu;
  const int s    = blockIdx.y;
  const int tid  = threadIdx.x;
  const int wave = tid >> 6, lane = tid & 63;
  const int quad = lane >> 4;
  const int n16  = lane & 15;
  const int nlane = blockIdx.x * 16 + n16;

  const unsigned short* As = A + (size_t)s * ASTRIDE;
  const unsigned int idx_base = (unsigned int)s * (unsigned int)(OVALID * KVALID)
                              + (unsigned int)nlane * (unsigned int)KVALID;

  f32x4 acc[4] = {f32x4{0,0,0,0}, f32x4{0,0,0,0}, f32x4{0,0,0,0}, f32x4{0,0,0,0}};

  auto load_step = [&](int st, bf16x8 (&af)[4], float4 (&q)[4]) {
    const int kb = st * 32 + quad * 8;
    #pragma unroll
    for (int mt = 0; mt < 4; ++mt)
      af[mt] = *reinterpret_cast<const bf16x8*>(
          As + (size_t)(mt * 16 + n16) * AROW + kb);
    const float4* mp = reinterpret_cast<const float4*>(
        msP + ((size_t)(kb >> 3) * OPITCH + nlane) * 8);
    #pragma unroll
    for (int h = 0; h < 4; ++h)
      q[h] = mp[h];
  };

  auto compute_step = [&](int st, bf16x8 (&af)[4], float4 (&q)[4]) {
    const int kb = st * 32 + quad * 8;
    unsigned int a[8], b[8], r[8];
    const unsigned int cb = idx_base + (unsigned int)kb + k1;
    TF8_FULL(r)

    // q[h] = (mu_k, mu_{k+1}, sg_k, sg_{k+1}) for k = kb + 2h
    i32x4 bp;
    #pragma unroll
    for (int h = 0; h < 4; ++h) {
      f32x2 g2 = bits_to_g2(r[2 * h], r[2 * h + 1]);
      f32x2 wv = pk_fma(mk2(q[h].z, q[h].w), g2, mk2(q[h].x, q[h].y));
      bp[h] = (int)cvt_pk_bf16(wv.x, wv.y);
    }
    bf16x8 bfrag = __builtin_bit_cast(bf16x8, bp);

    #pragma unroll
    for (int mt = 0; mt < 4; ++mt)
      acc[mt] = __builtin_amdgcn_mfma_f32_16x16x32_bf16(af[mt], bfrag, acc[mt], 0, 0, 0);
  };

  bf16x8 afA[4], afB[4];
  float4 qA[4], qB[4];
  int st = wave;
  if (st < NSTEPS) load_step(st, afA, qA);
  while (st < NSTEPS) {
    int n1 = st + 4;
    if (n1 < NSTEPS) load_step(n1, afB, qB);
    __builtin_amdgcn_sched_barrier(0);       // prefetch stays above compute
    compute_step(st, afA, qA);
    st = n1;
    if (st >= NSTEPS) break;
    int n2 = st + 4;
    if (n2 < NSTEPS) load_step(n2, afA, qA);
    __builtin_amdgcn_sched_barrier(0);
    compute_step(st, afB, qB);
    st = n2;
  }

  // reduce the 4 waves' partials through LDS
  __shared__ float red[4 * 16 * 64];   // 16 KB
  #pragma unroll
  for (int mt = 0; mt < 4; ++mt)
    #pragma unroll
    for (int r = 0; r < 4; ++r)
      red[(wave * 16 + mt * 4 + r) * 64 + lane] = acc[mt][r];
  __syncthreads();

  // epilogue: thread -> (m = tid>>2, n-quad = (tid&3)*4), 4 outputs each
  const int m   = tid >> 2;                    // 0..63
  const int nq  = (tid & 3) * 4;               // 0,4,8,12
  const int row = (m >> 4) * 4 + (m & 3);      // mt*4 + r
  const int col = ((m >> 2) & 3) * 16 + nq;    // quad*16 + nq

  float4 p0 = *reinterpret_cast<const float4*>(&red[(0 * 16 + row) * 64 + col]);
  float4 p1 = *reinterpret_cast<const float4*>(&red[(1 * 16 + row) * 64 + col]);
  float4 p2 = *reinterpret_cast<const float4*>(&red[(2 * 16 + row) * 64 + col]);
  float4 p3 = *reinterpret_cast<const float4*>(&red[(3 * 16 + row) * 64 + col]);
  float v0 = (p0.x + p1.x) + (p2.x + p3.x);
  float v1 = (p0.y + p1.y) + (p2.y + p3.y);
  float v2 = (p0.z + p1.z) + (p2.z + p3.z);
  float v3 = (p0.w + p1.w) + (p2.w + p3.w);

  const float4 b4 = *reinterpret_cast<const float4*>(
      &bS[s * OVALID + blockIdx.x * 16 + nq]);
  float o0 = fmaxf(v0 + b4.x, 0.0f), o1 = fmaxf(v1 + b4.y, 0.0f);
  float o2 = fmaxf(v2 + b4.z, 0.0f), o3 = fmaxf(v3 + b4.w, 0.0f);
  uint2 stv;
  stv.x = cvt_pk_bf16(o0, o1);
  stv.y = cvt_pk_bf16(o2, o3);
  *reinterpret_cast<uint2*>(
      Out + ((size_t)s * 64 + m) * OPITCH + blockIdx.x * 16 + nq) = stv;
}

// ---------------------------------------------------------------------------
// layer3_atomic: last layer with K-split ACROSS BLOCKS. grid dim3(4,150):
// block bx covers k-steps [bx*4, bx*4+4), one step per wave (RNG exactly once
// per (s,n,k)). 4-wave LDS reduce, then atomicAdd f32 partials onto d_out
// (pre-initialized with bias by bias3_out).
__global__ __launch_bounds__(256) void layer3_atomic(
    const unsigned short* __restrict__ A,   // bf16 [s][64][512]
    float* __restrict__ Out,                // f32 [s][64][10], bias pre-added
    const float2* __restrict__ msP,         // [64][16][8] (mu,mu,sg,sg), n-padded
    unsigned int k0, unsigned int k1)
{
  const unsigned int ks2 = k0 ^ k1 ^ 0x1BD11BDAu;
  const int s    = blockIdx.y;
  const int tid  = threadIdx.x;
  const int wave = tid >> 6, lane = tid & 63;
  const int quad = lane >> 4;
  const int n    = lane & 15;

  const unsigned short* As = A + (size_t)s * (64 * 512);
  const int st = blockIdx.x * 4 + wave;      // 0..15
  const int kb = st * 32 + quad * 8;
  const unsigned int idx_base = (unsigned int)s * 5120u + (unsigned int)n * 512u;

  // mu/sigma (padded n in [10,16) have mu=sigma=0 -> weight 0)
  const float4* mp = reinterpret_cast<const float4*>(
      msP + ((size_t)(kb >> 3) * 16 + n) * 8);
  float4 q[4];
  #pragma unroll
  for (int h = 0; h < 4; ++h) q[h] = mp[h];

  unsigned int a[8], b[8], r[8];
  const unsigned int cb = idx_base + (unsigned int)kb + k1;
  TF8_FULL(r)

  i32x4 bp;
  #pragma unroll
  for (int h = 0; h < 4; ++h) {
    f32x2 g2 = bits_to_g2(r[2 * h], r[2 * h + 1]);
    f32x2 wv = pk_fma(mk2(q[h].z, q[h].w), g2, mk2(q[h].x, q[h].y));
    bp[h] = (int)cvt_pk_bf16(wv.x, wv.y);
  }
  bf16x8 bfrag = __builtin_bit_cast(bf16x8, bp);

  f32x4 acc[4] = {f32x4{0,0,0,0}, f32x4{0,0,0,0}, f32x4{0,0,0,0}, f32x4{0,0,0,0}};
  #pragma unroll
  for (int mt = 0; mt < 4; ++mt) {
    bf16x8 afrag = *reinterpret_cast<const bf16x8*>(
        As + (size_t)(mt * 16 + n) * 512 + kb);
    acc[mt] = __builtin_amdgcn_mfma_f32_16x16x32_bf16(afrag, bfrag, acc[mt], 0, 0, 0);
  }

  __shared__ float red[4 * 16 * 64];   // 16 KB
  #pragma unroll
  for (int mt = 0; mt < 4; ++mt)
    #pragma unroll
    for (int rr = 0; rr < 4; ++rr)
      red[(wave * 16 + mt * 4 + rr) * 64 + lane] = acc[mt][rr];
  __syncthreads();

  const int m   = tid >> 2;                    // 0..63
  const int nq  = (tid & 3) * 4;               // 0,4,8,12
  const int row = (m >> 4) * 4 + (m & 3);
  const int col = ((m >> 2) & 3) * 16 + nq;

  float4 p0 = *reinterpret_cast<const float4*>(&red[(0 * 16 + row) * 64 + col]);
  float4 p1 = *reinterpret_cast<const float4*>(&red[(1 * 16 + row) * 64 + col]);
  float4 p2 = *reinterpret_cast<const float4*>(&red[(2 * 16 + row) * 64 + col]);
  float4 p3 = *reinterpret_cast<const float4*>(&red[(3 * 16 + row) * 64 + col]);
  float vv[4];
  vv[0] = (p0.x + p1.x) + (p2.x + p3.x);
  vv[1] = (p0.y + p1.y) + (p2.y + p3.y);
  vv[2] = (p0.z + p1.z) + (p2.z + p3.z);
  vv[3] = (p0.w + p1.w) + (p2.w + p3.w);

  #pragma unroll
  for (int jj = 0; jj < 4; ++jj) {
    int nn = nq + jj;
    if (nn < 10)
      atomicAdd(&Out[((size_t)s * 64 + m) * 10 + nn], vv[jj]);
  }
}

// ---------------------------------------------------------------------------
// Host-side threefry for jax.random.split(key(1), 8)
static void tf_host(unsigned int k0, unsigned int k1, unsigned int c0, unsigned int c1,
                    unsigned int* o0, unsigned int* o1)
{
  const unsigned int ks2 = k0 ^ k1 ^ 0x1BD11BDAu;
  unsigned int x0 = c0 + k0, x1 = c1 + k1;
  TF_R(13) TF_R(15) TF_R(26) TF_R(6)
  x0 += k1;  x1 += ks2 + 1u;
  TF_R(17) TF_R(29) TF_R(16) TF_R(24)
  x0 += ks2; x1 += k0 + 2u;
  TF_R(13) TF_R(15) TF_R(26) TF_R(6)
  x0 += k0;  x1 += k1 + 3u;
  TF_R(17) TF_R(29) TF_R(16) TF_R(24)
  x0 += k1;  x1 += ks2 + 4u;
  TF_R(13) TF_R(15) TF_R(26) TF_R(6)
  x0 += ks2; x1 += k0 + 5u;
  *o0 = x0; *o1 = x1;
}

extern "C" void kernel_launch(void* const* d_in, const int* in_sizes, int n_in,
                              void* d_out, int out_size, void* d_ws, size_t ws_size,
                              hipStream_t stream)
{
  (void)in_sizes; (void)n_in; (void)out_size; (void)ws_size;

  const float* x    = (const float*)d_in[0];
  const float* muW0 = (const float*)d_in[1];
  const float* mub0 = (const float*)d_in[2];
  const float* muW1 = (const float*)d_in[3];
  const float* mub1 = (const float*)d_in[4];
  const float* muW2 = (const float*)d_in[5];
  const float* mub2 = (const float*)d_in[6];
  const float* muW3 = (const float*)d_in[7];
  const float* mub3 = (const float*)d_in[8];
  const float* vW0  = (const float*)d_in[9];
  const float* vb0  = (const float*)d_in[10];
  const float* vW1  = (const float*)d_in[11];
  const float* vb1  = (const float*)d_in[12];
  const float* vW2  = (const float*)d_in[13];
  const float* vb2  = (const float*)d_in[14];
  const float* vW3  = (const float*)d_in[15];
  const float* vb3  = (const float*)d_in[16];

  // keys: split(key(1), 8) -> ks[0]:W0 ks[1]:b0 ks[2]:W1 ks[3]:b1 ...
  unsigned int key[8][2];
  for (unsigned int i = 0; i < 8; ++i)
    tf_host(0u, 1u, 0u, i, &key[i][0], &key[i][1]);

  // ws layout (~25.0 MB; hB aliases msP0 — msP0 is dead once L0 completes)
  char* ws = (char*)d_ws;
  unsigned short* xp = (unsigned short*)(ws);                 // 64*800*2 = 102,400
  unsigned short* hA = (unsigned short*)(ws + 106496);        // 150*64*512*2 = 9,830,400
  float* b0s  = (float*)(ws + 9936896);                       // 150*512*4 = 307,200
  float* b1s  = (float*)(ws + 10244096);
  float* b2s  = (float*)(ws + 10551296);
  float* b3s  = (float*)(ws + 10858496);                      // 150*10*4 (pad 8,192)
  float2* msP1 = (float2*)(ws + 10866688);                    // 2,097,152
  float2* msP2 = (float2*)(ws + 12963840);                    // 2,097,152
  float2* msP3 = (float2*)(ws + 15060992);                    // 65,536
  float2* msP0 = (float2*)(ws + 15126528);                    // 3,276,800
  unsigned short* hB = (unsigned short*)(ws + 15126528);      // aliases msP0

  xpad_kernel<<<200, 256, 0, stream>>>(x, xp);
  pack_kernel<<<3680, 256, 0, stream>>>(muW0, vW0, muW1, vW1, muW2, vW2, muW3, vW3,
                                        msP0, msP1, msP2, msP3);
  bias_kernel<<<906, 256, 0, stream>>>(mub0, vb0, b0s, mub1, vb1, b1s,
                                       mub2, vb2, b2s, mub3, vb3, b3s,
                                       key[1][0], key[1][1], key[3][0], key[3][1],
                                       key[5][0], key[5][1], key[7][0], key[7][1]);
  bias3_out<<<375, 256, 0, stream>>>((float*)d_out, b3s);

  // L0: x(64,784 pad 800) -> hA ; L1: hA -> hB (kills msP0) ; L2: hB -> hA ;
  // L3: hA -> out (K-split atomic, RNG x1)
  layer_fused<784, 800, 0,     800><<<dim3(32, 150), 256, 0, stream>>>(
      xp, hA, msP0, b0s, key[0][0], key[0][1]);
  layer_fused<512, 512, 32768, 512><<<dim3(32, 150), 256, 0, stream>>>(
      hA, hB, msP1, b1s, key[2][0], key[2][1]);
  layer_fused<512, 512, 32768, 512><<<dim3(32, 150), 256, 0, stream>>>(
      hB, hA, msP2, b2s, key[4][0], key[4][1]);
  layer3_atomic<<<dim3(4, 150), 256, 0, stream>>>(
      hA, (float*)d_out, msP3, key[6][0], key[6][1]);
}

// Round 4
// 404.809 us; speedup vs baseline: 1.0434x; 1.0318x over previous
//
#include <hip/hip_runtime.h>

// ---------------------------------------------------------------------------
// BNN MC forward: 150 weight samples of a 784->512->512->512->10 MLP, batch 64.
// Reproduces jax.random (threefry2x32, partitionable=True) exactly.
// R15 = R14 with two changes (both bit-exact):
//   a) ALL threefry rotations forced to v_alignbit_b32 via
//      __builtin_amdgcn_alignbit(x, x, 32-r). Hypothesis: LLVM was not fusing
//      the (x<<r)|(x>>(32-r)) idiom in the unrolled 8-chain stream (back-solved
//      ~2.4x VALU inflation vs hand model). alignbit is 1 instr, guaranteed.
//   b) packed-FP32 inline asm dropped (R14 showed it self-cancels via VGPR-pair
//      marshaling movs; VGPR 80->84, VALUBusy savings zero). Poly/wv scalar.
// Retained: merged threefry (init fold + v_add3 key injection), alignbit
// mantissa build + verbatim R11 x-formation, v_cvt_pk_bf16_f32 packing,
// (mu,mu,sg,sg) pack layout, L0 KPAD=800.
// ws usage ~25.0 MB (hB aliases msP0).
// ---------------------------------------------------------------------------

typedef short bf16x8 __attribute__((ext_vector_type(8)));
typedef int   i32x4  __attribute__((ext_vector_type(4)));
typedef float f32x4  __attribute__((ext_vector_type(4)));

// rotl(x,r) == rotr(x, 32-r) == v_alignbit_b32(x, x, 32-r) — single instr.
__device__ __forceinline__ unsigned int rotl_ab(unsigned int x, int r)
{
  return __builtin_amdgcn_alignbit(x, x, 32 - r);
}

// a -> low 16, b -> high 16, RNE (== manual RNE trick for all finite inputs).
// HW-verified on gfx950 (learn_hip m214v22).
__device__ __forceinline__ unsigned int cvt_pk_bf16(float a, float b)
{
  unsigned int d;
  asm("v_cvt_pk_bf16_f32 %0, %1, %2" : "=v"(d) : "v"(a), "v"(b));
  return d;
}

#define TF_R(r) { x0 += x1; x1 = (x1 << (r)) | (x1 >> (32 - (r))); x1 ^= x0; }

// 8-chain round-major threefry pieces (a[8], b[8] in scope)
#define TF8(r) { _Pragma("unroll") for (int j = 0; j < 8; ++j) { \
    a[j] += b[j]; b[j] = rotl_ab(b[j], (r)) ^ a[j]; } }
// rot+xor only (the preceding a+=b has been absorbed elsewhere)
#define ROTX8(r) { _Pragma("unroll") for (int j = 0; j < 8; ++j) { \
    b[j] = rotl_ab(b[j], (r)) ^ a[j]; } }
// key injection merged with the NEXT round's a+=b:  b += kkb; a = a + b + kka
// (associativity mod 2^32 -> bit-exact; compiles to v_add + v_add3)
#define INJM8(kka, kkb) { const unsigned int _ka = (kka), _kb = (kkb); \
    _Pragma("unroll") for (int j = 0; j < 8; ++j) { \
    b[j] += _kb; a[j] = a[j] + b[j] + _ka; } }

// full merged 20-round threefry on the 8 chains; needs a[],b[],cb,k0,k1,ks2
// in scope; leaves out[j] = x0^x1 in rout[]. Verified vs jax in R14 (passed).
#define TF8_FULL(rout) { \
    const unsigned int _kc = cb + k0; \
    _Pragma("unroll") for (int j = 0; j < 8; ++j) { \
      b[j] = cb + (unsigned int)j; a[j] = _kc + (unsigned int)j; } \
    ROTX8(13) TF8(15) TF8(26) TF8(6) \
    INJM8(k1, ks2 + 1u)  ROTX8(17) TF8(29) TF8(16) TF8(24) \
    INJM8(ks2, k0 + 2u)  ROTX8(13) TF8(15) TF8(26) TF8(6) \
    INJM8(k0, k1 + 3u)   ROTX8(17) TF8(29) TF8(16) TF8(24) \
    INJM8(k1, ks2 + 4u)  ROTX8(13) TF8(15) TF8(26) TF8(6) \
    const unsigned int _f1 = k0 + 5u; \
    _Pragma("unroll") for (int j = 0; j < 8; ++j) \
      rout[j] = (a[j] + ks2) ^ (b[j] + _f1); }

// Threefry-2x32, counter (0, c1), returns x0^x1 — scalar version (bias kernel)
__device__ __forceinline__ unsigned int tf_xor(unsigned int k0, unsigned int k1,
                                               unsigned int c1)
{
  const unsigned int ks2 = k0 ^ k1 ^ 0x1BD11BDAu;
  unsigned int x0 = k0;          // c0 = 0 (+ ks[0])
  unsigned int x1 = c1 + k1;
  TF_R(13) TF_R(15) TF_R(26) TF_R(6)
  x0 += k1;  x1 += ks2 + 1u;
  TF_R(17) TF_R(29) TF_R(16) TF_R(24)
  x0 += ks2; x1 += k0 + 2u;
  TF_R(13) TF_R(15) TF_R(26) TF_R(6)
  x0 += k0;  x1 += k1 + 3u;
  TF_R(17) TF_R(29) TF_R(16) TF_R(24)
  x0 += k1;  x1 += ks2 + 4u;
  TF_R(13) TF_R(15) TF_R(26) TF_R(6)
  x0 += ks2; x1 += k0 + 5u;
  return x0 ^ x1;
}

// rare erfinv tail (w >= 5, p ~ 0.34%) — identical to R6..R14 selected values
__device__ __forceinline__ float erfinv_tail(float L)
{
  float w  = L * -0.6931472f;
  float t2 = sqrtf(w) - 3.0f;
  float pt = 0.00573950773f;
  pt = __builtin_fmaf(pt, t2, -0.0076224613f);
  pt = __builtin_fmaf(pt, t2, 0.00943887047f);
  pt = __builtin_fmaf(pt, t2, 1.00167406f);
  pt = __builtin_fmaf(pt, t2, 2.83297682f);
  return pt;
}

// mantissa build: (r>>9)|0x3F800000 in one v_alignbit_b32 (exact, R14-proven).
__device__ __forceinline__ float bits_to_f(unsigned int r)
{
  return __uint_as_float(__builtin_amdgcn_alignbit(0x7Fu, r, 9u)) - 1.0f;
}

// bits -> g where eps = sqrt(2)*g; caller folds sqrt(2) into sigma.
// x-formation is VERBATIM R11: x = fma(f, 2, -0.99999994f) — x never hits
// +-1, so log2(1-x^2) is always finite (the R12/R13 literal bug).
__device__ __forceinline__ float bits_to_g(unsigned int r)
{
  float f = bits_to_f(r);
  float x = __builtin_fmaf(f, 2.0f, -0.99999994f);
  float L = __log2f(__builtin_fmaf(-x, x, 1.0f));             // log2(1-x^2) <= 0
  float t  = __builtin_fmaf(L, -0.6931472f, -2.5f);
  float p = -4.39150654e-06f;
  p = __builtin_fmaf(p, t, 0.00021858087f);
  p = __builtin_fmaf(p, t, -0.00125372503f);
  p = __builtin_fmaf(p, t, -0.00417768164f);
  p = __builtin_fmaf(p, t, 0.246640727f);
  p = __builtin_fmaf(p, t, 1.50140941f);
  if (__builtin_expect(L <= -7.2134752f, 0))
    p = erfinv_tail(L);
  return p * x;
}

__device__ __forceinline__ unsigned short f32_to_bf16_rne(float v)
{
  unsigned int u = __float_as_uint(v);
  unsigned int r = (u + 0x7FFFu + ((u >> 16) & 1u)) >> 16;   // RNE
  return (unsigned short)r;
}

// ---------------------------------------------------------------------------
// x (64,784) fp32 -> bf16, K padded 784 -> 800 with zeros
__global__ __launch_bounds__(256) void xpad_kernel(const float* __restrict__ x,
                                                   unsigned short* __restrict__ xp)
{
  int i = blockIdx.x * 256 + threadIdx.x;          // grid 200 -> 51200 == 64*800
  if (i >= 64 * 800) return;
  int m = i / 800, k = i - m * 800;
  float v = (k < 784) ? x[m * 784 + k] : 0.0f;
  xp[i] = f32_to_bf16_rne(v);
}

// ---------------------------------------------------------------------------
// Pack (mu, exp(v)*sqrt2) into [k/8][n][8] float2, zero-padded in k and n.
// Layout: each 16B group holds (mu_k, mu_{k+1}, sg_k, sg_{k+1}).
__global__ __launch_bounds__(256) void pack_kernel(
    const float* __restrict__ muW0, const float* __restrict__ vW0,
    const float* __restrict__ muW1, const float* __restrict__ vW1,
    const float* __restrict__ muW2, const float* __restrict__ vW2,
    const float* __restrict__ muW3, const float* __restrict__ vW3,
    float2* __restrict__ msP0, float2* __restrict__ msP1,
    float2* __restrict__ msP2, float2* __restrict__ msP3)
{
  int b = blockIdx.x, tid = threadIdx.x;
  const float* mu; const float* v; float2* o;
  int KV, NV, osh, base;
  if (b < 1600)      { mu = muW0; v = vW0; o = msP0; KV = 784; NV = 512; osh = 9; base = 0;    }
  else if (b < 2624) { mu = muW1; v = vW1; o = msP1; KV = 512; NV = 512; osh = 9; base = 1600; }
  else if (b < 3648) { mu = muW2; v = vW2; o = msP2; KV = 512; NV = 512; osh = 9; base = 2624; }
  else               { mu = muW3; v = vW3; o = msP3; KV = 512; NV = 10;  osh = 4; base = 3648; }
  int e = (b - base) * 256 + tid;
  int k = (e & 7) | ((e >> (3 + osh)) << 3);
  int n = (e >> 3) & ((1 << osh) - 1);
  float mu_v = 0.0f, sg_v = 0.0f;
  if (k < KV && n < NV) {
    mu_v = mu[n * KV + k];
    sg_v = __expf(v[n * KV + k]) * 1.41421356237f;
  }
  // pair (e even, e+1): same n, k and k+1 (pairs never straddle KV; KV even)
  float mu_o = __shfl_xor(mu_v, 1);
  float sg_o = __shfl_xor(sg_v, 1);
  float2 r;
  if ((e & 1) == 0) { r.x = mu_v; r.y = mu_o; }
  else              { r.x = sg_o; r.y = sg_v; }
  o[e] = r;
}

// ---------------------------------------------------------------------------
// Sample all 4 bias tensors -> fp32 in ws.  b_l[s][o] = mu[o] + exp(v[o])*eps
__global__ __launch_bounds__(256) void bias_kernel(
    const float* __restrict__ mu0, const float* __restrict__ v0, float* __restrict__ o0,
    const float* __restrict__ mu1, const float* __restrict__ v1, float* __restrict__ o1,
    const float* __restrict__ mu2, const float* __restrict__ v2, float* __restrict__ o2,
    const float* __restrict__ mu3, const float* __restrict__ v3, float* __restrict__ o3,
    unsigned int k00, unsigned int k01, unsigned int k10, unsigned int k11,
    unsigned int k20, unsigned int k21, unsigned int k30, unsigned int k31)
{
  int b = blockIdx.x, tid = threadIdx.x;
  int seg = b / 300; if (seg > 3) seg = 3;
  const float* mu; const float* v; float* o; unsigned int ka, kb; int n;
  if      (seg == 0) { mu = mu0; v = v0; o = o0; ka = k00; kb = k01; n = 76800; }
  else if (seg == 1) { mu = mu1; v = v1; o = o1; ka = k10; kb = k11; n = 76800; }
  else if (seg == 2) { mu = mu2; v = v2; o = o2; ka = k20; kb = k21; n = 76800; }
  else               { mu = mu3; v = v3; o = o3; ka = k30; kb = k31; n = 1500;  }
  int e = (b - seg * 300) * 256 + tid;
  if (e >= n) return;
  int oo = (seg == 3) ? (e % 10) : (e & 511);
  float eps = 1.41421356237f * bits_to_g(tf_xor(ka, kb, (unsigned int)e));
  o[e] = __builtin_fmaf(__expf(v[oo]), eps, mu[oo]);
}

// ---------------------------------------------------------------------------
// bias3_out: initialize d_out[s][m][n] = b3s[s][n]  (150*64*10 = 96000 f32)
__global__ __launch_bounds__(256) void bias3_out(float* __restrict__ Out,
                                                 const float* __restrict__ b3s)
{
  int i = blockIdx.x * 256 + threadIdx.x;   // grid 375
  if (i >= 96000) return;
  int s = i / 640;
  int rem = i - s * 640;
  int n = rem % 10;
  Out[i] = b3s[s * 10 + n];
}

// ---------------------------------------------------------------------------
// Fused big layer (R7 structure, grid dim3(32,150)):
//   block = 4 waves, one 16-col n-range x all 64 m x full K; K-split across
//   waves; ping-pong register prefetch pinned with sched_barrier(0);
//   LDS reduce; epilogue bias+relu, bf16 out.
// amdgpu_waves_per_eu(1,4): scheduler targets 4 waves/EU, freeing <=128 VGPR.
// mfma_f32_16x16x32_bf16: A/B frag lane holds row (lane&15), k=(lane>>4)*8+j;
// C/D lane holds col n=(lane&15), rows m=(lane>>4)*4+reg.
template<int KVALID, int KPAD, int ASTRIDE, int AROW>
__global__
__attribute__((amdgpu_flat_work_group_size(256, 256)))
__attribute__((amdgpu_waves_per_eu(1, 4)))
void layer_fused(
    const unsigned short* __restrict__ A,   // bf16 [s][64][AROW] (ASTRIDE=0: shared x)
    unsigned short* __restrict__ Out,       // bf16 [s][64][512]
    const float2* __restrict__ msP,         // [KPAD/8][512][8] (mu,mu,sg,sg pairs)
    const float* __restrict__ bS,           // [s][512]
    unsigned int k0, unsigned int k1)
{
  constexpr int NSTEPS = KPAD / 32;
  constexpr int OVALID = 512, OPITCH = 512;
  const unsigned int ks2 = k0 ^ k1 ^ 0x1BD11BDAu;
  const int s    = blockIdx.y;
  const int tid  = threadIdx.x;
  const int wave = tid >> 6, lane = tid & 63;
  const int quad = lane >> 4;
  const int n16  = lane & 15;
  const int nlane = blockIdx.x * 16 + n16;

  const unsigned short* As = A + (size_t)s * ASTRIDE;
  const unsigned int idx_base = (unsigned int)s * (unsigned int)(OVALID * KVALID)
                              + (unsigned int)nlane * (unsigned int)KVALID;

  f32x4 acc[4] = {f32x4{0,0,0,0}, f32x4{0,0,0,0}, f32x4{0,0,0,0}, f32x4{0,0,0,0}};

  auto load_step = [&](int st, bf16x8 (&af)[4], float4 (&q)[4]) {
    const int kb = st * 32 + quad * 8;
    #pragma unroll
    for (int mt = 0; mt < 4; ++mt)
      af[mt] = *reinterpret_cast<const bf16x8*>(
          As + (size_t)(mt * 16 + n16) * AROW + kb);
    const float4* mp = reinterpret_cast<const float4*>(
        msP + ((size_t)(kb >> 3) * OPITCH + nlane) * 8);
    #pragma unroll
    for (int h = 0; h < 4; ++h)
      q[h] = mp[h];
  };

  auto compute_step = [&](int st, bf16x8 (&af)[4], float4 (&q)[4]) {
    const int kb = st * 32 + quad * 8;
    unsigned int a[8], b[8], r[8];
    const unsigned int cb = idx_base + (unsigned int)kb + k1;
    TF8_FULL(r)

    float g[8];
    #pragma unroll
    for (int j = 0; j < 8; ++j)
      g[j] = bits_to_g(r[j]);

    // q[h] = (mu_k, mu_{k+1}, sg_k, sg_{k+1}) for k = kb + 2h
    i32x4 bp;
    #pragma unroll
    for (int h = 0; h < 4; ++h) {
      float w0 = __builtin_fmaf(q[h].z, g[2 * h],     q[h].x);
      float w1 = __builtin_fmaf(q[h].w, g[2 * h + 1], q[h].y);
      bp[h] = (int)cvt_pk_bf16(w0, w1);
    }
    bf16x8 bfrag = __builtin_bit_cast(bf16x8, bp);

    #pragma unroll
    for (int mt = 0; mt < 4; ++mt)
      acc[mt] = __builtin_amdgcn_mfma_f32_16x16x32_bf16(af[mt], bfrag, acc[mt], 0, 0, 0);
  };

  bf16x8 afA[4], afB[4];
  float4 qA[4], qB[4];
  int st = wave;
  if (st < NSTEPS) load_step(st, afA, qA);
  while (st < NSTEPS) {
    int n1 = st + 4;
    if (n1 < NSTEPS) load_step(n1, afB, qB);
    __builtin_amdgcn_sched_barrier(0);       // prefetch stays above compute
    compute_step(st, afA, qA);
    st = n1;
    if (st >= NSTEPS) break;
    int n2 = st + 4;
    if (n2 < NSTEPS) load_step(n2, afA, qA);
    __builtin_amdgcn_sched_barrier(0);
    compute_step(st, afB, qB);
    st = n2;
  }

  // reduce the 4 waves' partials through LDS
  __shared__ float red[4 * 16 * 64];   // 16 KB
  #pragma unroll
  for (int mt = 0; mt < 4; ++mt)
    #pragma unroll
    for (int r = 0; r < 4; ++r)
      red[(wave * 16 + mt * 4 + r) * 64 + lane] = acc[mt][r];
  __syncthreads();

  // epilogue: thread -> (m = tid>>2, n-quad = (tid&3)*4), 4 outputs each
  const int m   = tid >> 2;                    // 0..63
  const int nq  = (tid & 3) * 4;               // 0,4,8,12
  const int row = (m >> 4) * 4 + (m & 3);      // mt*4 + r
  const int col = ((m >> 2) & 3) * 16 + nq;    // quad*16 + nq

  float4 p0 = *reinterpret_cast<const float4*>(&red[(0 * 16 + row) * 64 + col]);
  float4 p1 = *reinterpret_cast<const float4*>(&red[(1 * 16 + row) * 64 + col]);
  float4 p2 = *reinterpret_cast<const float4*>(&red[(2 * 16 + row) * 64 + col]);
  float4 p3 = *reinterpret_cast<const float4*>(&red[(3 * 16 + row) * 64 + col]);
  float v0 = (p0.x + p1.x) + (p2.x + p3.x);
  float v1 = (p0.y + p1.y) + (p2.y + p3.y);
  float v2 = (p0.z + p1.z) + (p2.z + p3.z);
  float v3 = (p0.w + p1.w) + (p2.w + p3.w);

  const float4 b4 = *reinterpret_cast<const float4*>(
      &bS[s * OVALID + blockIdx.x * 16 + nq]);
  float o0 = fmaxf(v0 + b4.x, 0.0f), o1 = fmaxf(v1 + b4.y, 0.0f);
  float o2 = fmaxf(v2 + b4.z, 0.0f), o3 = fmaxf(v3 + b4.w, 0.0f);
  uint2 stv;
  stv.x = cvt_pk_bf16(o0, o1);
  stv.y = cvt_pk_bf16(o2, o3);
  *reinterpret_cast<uint2*>(
      Out + ((size_t)s * 64 + m) * OPITCH + blockIdx.x * 16 + nq) = stv;
}

// ---------------------------------------------------------------------------
// layer3_atomic: last layer with K-split ACROSS BLOCKS. grid dim3(4,150):
// block bx covers k-steps [bx*4, bx*4+4), one step per wave (RNG exactly once
// per (s,n,k)). 4-wave LDS reduce, then atomicAdd f32 partials onto d_out
// (pre-initialized with bias by bias3_out).
__global__ __launch_bounds__(256) void layer3_atomic(
    const unsigned short* __restrict__ A,   // bf16 [s][64][512]
    float* __restrict__ Out,                // f32 [s][64][10], bias pre-added
    const float2* __restrict__ msP,         // [64][16][8] (mu,mu,sg,sg), n-padded
    unsigned int k0, unsigned int k1)
{
  const unsigned int ks2 = k0 ^ k1 ^ 0x1BD11BDAu;
  const int s    = blockIdx.y;
  const int tid  = threadIdx.x;
  const int wave = tid >> 6, lane = tid & 63;
  const int quad = lane >> 4;
  const int n    = lane & 15;

  const unsigned short* As = A + (size_t)s * (64 * 512);
  const int st = blockIdx.x * 4 + wave;      // 0..15
  const int kb = st * 32 + quad * 8;
  const unsigned int idx_base = (unsigned int)s * 5120u + (unsigned int)n * 512u;

  // mu/sigma (padded n in [10,16) have mu=sigma=0 -> weight 0)
  const float4* mp = reinterpret_cast<const float4*>(
      msP + ((size_t)(kb >> 3) * 16 + n) * 8);
  float4 q[4];
  #pragma unroll
  for (int h = 0; h < 4; ++h) q[h] = mp[h];

  unsigned int a[8], b[8], r[8];
  const unsigned int cb = idx_base + (unsigned int)kb + k1;
  TF8_FULL(r)

  float g[8];
  #pragma unroll
  for (int j = 0; j < 8; ++j)
    g[j] = bits_to_g(r[j]);

  i32x4 bp;
  #pragma unroll
  for (int h = 0; h < 4; ++h) {
    float w0 = __builtin_fmaf(q[h].z, g[2 * h],     q[h].x);
    float w1 = __builtin_fmaf(q[h].w, g[2 * h + 1], q[h].y);
    bp[h] = (int)cvt_pk_bf16(w0, w1);
  }
  bf16x8 bfrag = __builtin_bit_cast(bf16x8, bp);

  f32x4 acc[4] = {f32x4{0,0,0,0}, f32x4{0,0,0,0}, f32x4{0,0,0,0}, f32x4{0,0,0,0}};
  #pragma unroll
  for (int mt = 0; mt < 4; ++mt) {
    bf16x8 afrag = *reinterpret_cast<const bf16x8*>(
        As + (size_t)(mt * 16 + n) * 512 + kb);
    acc[mt] = __builtin_amdgcn_mfma_f32_16x16x32_bf16(afrag, bfrag, acc[mt], 0, 0, 0);
  }

  __shared__ float red[4 * 16 * 64];   // 16 KB
  #pragma unroll
  for (int mt = 0; mt < 4; ++mt)
    #pragma unroll
    for (int rr = 0; rr < 4; ++rr)
      red[(wave * 16 + mt * 4 + rr) * 64 + lane] = acc[mt][rr];
  __syncthreads();

  const int m   = tid >> 2;                    // 0..63
  const int nq  = (tid & 3) * 4;               // 0,4,8,12
  const int row = (m >> 4) * 4 + (m & 3);
  const int col = ((m >> 2) & 3) * 16 + nq;

  float4 p0 = *reinterpret_cast<const float4*>(&red[(0 * 16 + row) * 64 + col]);
  float4 p1 = *reinterpret_cast<const float4*>(&red[(1 * 16 + row) * 64 + col]);
  float4 p2 = *reinterpret_cast<const float4*>(&red[(2 * 16 + row) * 64 + col]);
  float4 p3 = *reinterpret_cast<const float4*>(&red[(3 * 16 + row) * 64 + col]);
  float vv[4];
  vv[0] = (p0.x + p1.x) + (p2.x + p3.x);
  vv[1] = (p0.y + p1.y) + (p2.y + p3.y);
  vv[2] = (p0.z + p1.z) + (p2.z + p3.z);
  vv[3] = (p0.w + p1.w) + (p2.w + p3.w);

  #pragma unroll
  for (int jj = 0; jj < 4; ++jj) {
    int nn = nq + jj;
    if (nn < 10)
      atomicAdd(&Out[((size_t)s * 64 + m) * 10 + nn], vv[jj]);
  }
}

// ---------------------------------------------------------------------------
// Host-side threefry for jax.random.split(key(1), 8)
static void tf_host(unsigned int k0, unsigned int k1, unsigned int c0, unsigned int c1,
                    unsigned int* o0, unsigned int* o1)
{
  const unsigned int ks2 = k0 ^ k1 ^ 0x1BD11BDAu;
  unsigned int x0 = c0 + k0, x1 = c1 + k1;
  TF_R(13) TF_R(15) TF_R(26) TF_R(6)
  x0 += k1;  x1 += ks2 + 1u;
  TF_R(17) TF_R(29) TF_R(16) TF_R(24)
  x0 += ks2; x1 += k0 + 2u;
  TF_R(13) TF_R(15) TF_R(26) TF_R(6)
  x0 += k0;  x1 += k1 + 3u;
  TF_R(17) TF_R(29) TF_R(16) TF_R(24)
  x0 += k1;  x1 += ks2 + 4u;
  TF_R(13) TF_R(15) TF_R(26) TF_R(6)
  x0 += ks2; x1 += k0 + 5u;
  *o0 = x0; *o1 = x1;
}

extern "C" void kernel_launch(void* const* d_in, const int* in_sizes, int n_in,
                              void* d_out, int out_size, void* d_ws, size_t ws_size,
                              hipStream_t stream)
{
  (void)in_sizes; (void)n_in; (void)out_size; (void)ws_size;

  const float* x    = (const float*)d_in[0];
  const float* muW0 = (const float*)d_in[1];
  const float* mub0 = (const float*)d_in[2];
  const float* muW1 = (const float*)d_in[3];
  const float* mub1 = (const float*)d_in[4];
  const float* muW2 = (const float*)d_in[5];
  const float* mub2 = (const float*)d_in[6];
  const float* muW3 = (const float*)d_in[7];
  const float* mub3 = (const float*)d_in[8];
  const float* vW0  = (const float*)d_in[9];
  const float* vb0  = (const float*)d_in[10];
  const float* vW1  = (const float*)d_in[11];
  const float* vb1  = (const float*)d_in[12];
  const float* vW2  = (const float*)d_in[13];
  const float* vb2  = (const float*)d_in[14];
  const float* vW3  = (const float*)d_in[15];
  const float* vb3  = (const float*)d_in[16];

  // keys: split(key(1), 8) -> ks[0]:W0 ks[1]:b0 ks[2]:W1 ks[3]:b1 ...
  unsigned int key[8][2];
  for (unsigned int i = 0; i < 8; ++i)
    tf_host(0u, 1u, 0u, i, &key[i][0], &key[i][1]);

  // ws layout (~25.0 MB; hB aliases msP0 — msP0 is dead once L0 completes)
  char* ws = (char*)d_ws;
  unsigned short* xp = (unsigned short*)(ws);                 // 64*800*2 = 102,400
  unsigned short* hA = (unsigned short*)(ws + 106496);        // 150*64*512*2 = 9,830,400
  float* b0s  = (float*)(ws + 9936896);                       // 150*512*4 = 307,200
  float* b1s  = (float*)(ws + 10244096);
  float* b2s  = (float*)(ws + 10551296);
  float* b3s  = (float*)(ws + 10858496);                      // 150*10*4 (pad 8,192)
  float2* msP1 = (float2*)(ws + 10866688);                    // 2,097,152
  float2* msP2 = (float2*)(ws + 12963840);                    // 2,097,152
  float2* msP3 = (float2*)(ws + 15060992);                    // 65,536
  float2* msP0 = (float2*)(ws + 15126528);                    // 3,276,800
  unsigned short* hB = (unsigned short*)(ws + 15126528);      // aliases msP0

  xpad_kernel<<<200, 256, 0, stream>>>(x, xp);
  pack_kernel<<<3680, 256, 0, stream>>>(muW0, vW0, muW1, vW1, muW2, vW2, muW3, vW3,
                                        msP0, msP1, msP2, msP3);
  bias_kernel<<<906, 256, 0, stream>>>(mub0, vb0, b0s, mub1, vb1, b1s,
                                       mub2, vb2, b2s, mub3, vb3, b3s,
                                       key[1][0], key[1][1], key[3][0], key[3][1],
                                       key[5][0], key[5][1], key[7][0], key[7][1]);
  bias3_out<<<375, 256, 0, stream>>>((float*)d_out, b3s);

  // L0: x(64,784 pad 800) -> hA ; L1: hA -> hB (kills msP0) ; L2: hB -> hA ;
  // L3: hA -> out (K-split atomic, RNG x1)
  layer_fused<784, 800, 0,     800><<<dim3(32, 150), 256, 0, stream>>>(
      xp, hA, msP0, b0s, key[0][0], key[0][1]);
  layer_fused<512, 512, 32768, 512><<<dim3(32, 150), 256, 0, stream>>>(
      hA, hB, msP1, b1s, key[2][0], key[2][1]);
  layer_fused<512, 512, 32768, 512><<<dim3(32, 150), 256, 0, stream>>>(
      hB, hA, msP2, b2s, key[4][0], key[4][1]);
  layer3_atomic<<<dim3(4, 150), 256, 0, stream>>>(
      hA, (float*)d_out, msP3, key[6][0], key[6][1]);
}

// Round 6
// 393.157 us; speedup vs baseline: 1.0743x; 1.0296x over previous
//
#include <hip/hip_runtime.h>

// ---------------------------------------------------------------------------
// BNN MC forward: 150 weight samples of a 784->512->512->512->10 MLP, batch 64.
// Reproduces jax.random (threefry2x32, partitionable=True) exactly.
// R17 = R16 with the compile fix (__sqrtf -> __builtin_amdgcn_sqrtf; HIP has
// no __sqrtf device function). Content otherwise identical to R16:
//   a) layer_fused K-loop fully unrolled: each wave does NSTEPS/4 uniform
//      steps (+1 tail step for wave<NSTEPS%4, L0 only). Step index is
//      compile-time -> A-loads become base+imm-offset, cb becomes literal
//      adds, loop compare/branch and per-step address mul-chains vanish.
//   b) erfinv tail uses v_sqrt_f32 (<=1ulp on 0.34% of draws, weight error
//      ~2e-8 -- far below the 0.305 threshold).
// Retained from R15: alignbit rotations, merged threefry (init fold + v_add3
// key injection), alignbit mantissa build + verbatim R11 x-formation,
// v_cvt_pk_bf16_f32 packing, (mu,mu,sg,sg) pack layout, L0 KPAD=800.
// ws usage ~25.0 MB (hB aliases msP0).
// ---------------------------------------------------------------------------

typedef short bf16x8 __attribute__((ext_vector_type(8)));
typedef int   i32x4  __attribute__((ext_vector_type(4)));
typedef float f32x4  __attribute__((ext_vector_type(4)));

// rotl(x,r) == rotr(x, 32-r) == v_alignbit_b32(x, x, 32-r) — single instr.
__device__ __forceinline__ unsigned int rotl_ab(unsigned int x, int r)
{
  return __builtin_amdgcn_alignbit(x, x, 32 - r);
}

// a -> low 16, b -> high 16, RNE (== manual RNE trick for all finite inputs).
// HW-verified on gfx950 (learn_hip m214v22).
__device__ __forceinline__ unsigned int cvt_pk_bf16(float a, float b)
{
  unsigned int d;
  asm("v_cvt_pk_bf16_f32 %0, %1, %2" : "=v"(d) : "v"(a), "v"(b));
  return d;
}

#define TF_R(r) { x0 += x1; x1 = (x1 << (r)) | (x1 >> (32 - (r))); x1 ^= x0; }

// 8-chain round-major threefry pieces (a[8], b[8] in scope)
#define TF8(r) { _Pragma("unroll") for (int j = 0; j < 8; ++j) { \
    a[j] += b[j]; b[j] = rotl_ab(b[j], (r)) ^ a[j]; } }
// rot+xor only (the preceding a+=b has been absorbed elsewhere)
#define ROTX8(r) { _Pragma("unroll") for (int j = 0; j < 8; ++j) { \
    b[j] = rotl_ab(b[j], (r)) ^ a[j]; } }
// key injection merged with the NEXT round's a+=b:  b += kkb; a = a + b + kka
// (associativity mod 2^32 -> bit-exact; compiles to v_add + v_add3)
#define INJM8(kka, kkb) { const unsigned int _ka = (kka), _kb = (kkb); \
    _Pragma("unroll") for (int j = 0; j < 8; ++j) { \
    b[j] += _kb; a[j] = a[j] + b[j] + _ka; } }

// full merged 20-round threefry on the 8 chains; needs a[],b[],cb,k0,k1,ks2
// in scope; leaves out[j] = x0^x1 in rout[]. Verified vs jax (R14/R15 passed).
#define TF8_FULL(rout) { \
    const unsigned int _kc = cb + k0; \
    _Pragma("unroll") for (int j = 0; j < 8; ++j) { \
      b[j] = cb + (unsigned int)j; a[j] = _kc + (unsigned int)j; } \
    ROTX8(13) TF8(15) TF8(26) TF8(6) \
    INJM8(k1, ks2 + 1u)  ROTX8(17) TF8(29) TF8(16) TF8(24) \
    INJM8(ks2, k0 + 2u)  ROTX8(13) TF8(15) TF8(26) TF8(6) \
    INJM8(k0, k1 + 3u)   ROTX8(17) TF8(29) TF8(16) TF8(24) \
    INJM8(k1, ks2 + 4u)  ROTX8(13) TF8(15) TF8(26) TF8(6) \
    const unsigned int _f1 = k0 + 5u; \
    _Pragma("unroll") for (int j = 0; j < 8; ++j) \
      rout[j] = (a[j] + ks2) ^ (b[j] + _f1); }

// Threefry-2x32, counter (0, c1), returns x0^x1 — scalar version (bias kernel)
__device__ __forceinline__ unsigned int tf_xor(unsigned int k0, unsigned int k1,
                                               unsigned int c1)
{
  const unsigned int ks2 = k0 ^ k1 ^ 0x1BD11BDAu;
  unsigned int x0 = k0;          // c0 = 0 (+ ks[0])
  unsigned int x1 = c1 + k1;
  TF_R(13) TF_R(15) TF_R(26) TF_R(6)
  x0 += k1;  x1 += ks2 + 1u;
  TF_R(17) TF_R(29) TF_R(16) TF_R(24)
  x0 += ks2; x1 += k0 + 2u;
  TF_R(13) TF_R(15) TF_R(26) TF_R(6)
  x0 += k0;  x1 += k1 + 3u;
  TF_R(17) TF_R(29) TF_R(16) TF_R(24)
  x0 += k1;  x1 += ks2 + 4u;
  TF_R(13) TF_R(15) TF_R(26) TF_R(6)
  x0 += ks2; x1 += k0 + 5u;
  return x0 ^ x1;
}

// rare erfinv tail (w >= 5, p ~ 0.34%). v_sqrt_f32: <=1ulp on t2 -> weight
// error ~2e-8 (threshold 0.305). Otherwise identical selection.
__device__ __forceinline__ float erfinv_tail(float L)
{
  float w  = L * -0.6931472f;
  float t2 = __builtin_amdgcn_sqrtf(w) - 3.0f;
  float pt = 0.00573950773f;
  pt = __builtin_fmaf(pt, t2, -0.0076224613f);
  pt = __builtin_fmaf(pt, t2, 0.00943887047f);
  pt = __builtin_fmaf(pt, t2, 1.00167406f);
  pt = __builtin_fmaf(pt, t2, 2.83297682f);
  return pt;
}

// mantissa build: (r>>9)|0x3F800000 in one v_alignbit_b32 (exact, R14-proven).
__device__ __forceinline__ float bits_to_f(unsigned int r)
{
  return __uint_as_float(__builtin_amdgcn_alignbit(0x7Fu, r, 9u)) - 1.0f;
}

// bits -> g where eps = sqrt(2)*g; caller folds sqrt(2) into sigma.
// x-formation is VERBATIM R11: x = fma(f, 2, -0.99999994f) — x never hits
// +-1, so log2(1-x^2) is always finite (the R12/R13 literal bug).
__device__ __forceinline__ float bits_to_g(unsigned int r)
{
  float f = bits_to_f(r);
  float x = __builtin_fmaf(f, 2.0f, -0.99999994f);
  float L = __log2f(__builtin_fmaf(-x, x, 1.0f));             // log2(1-x^2) <= 0
  float t  = __builtin_fmaf(L, -0.6931472f, -2.5f);
  float p = -4.39150654e-06f;
  p = __builtin_fmaf(p, t, 0.00021858087f);
  p = __builtin_fmaf(p, t, -0.00125372503f);
  p = __builtin_fmaf(p, t, -0.00417768164f);
  p = __builtin_fmaf(p, t, 0.246640727f);
  p = __builtin_fmaf(p, t, 1.50140941f);
  if (__builtin_expect(L <= -7.2134752f, 0))
    p = erfinv_tail(L);
  return p * x;
}

__device__ __forceinline__ unsigned short f32_to_bf16_rne(float v)
{
  unsigned int u = __float_as_uint(v);
  unsigned int r = (u + 0x7FFFu + ((u >> 16) & 1u)) >> 16;   // RNE
  return (unsigned short)r;
}

// ---------------------------------------------------------------------------
// x (64,784) fp32 -> bf16, K padded 784 -> 800 with zeros
__global__ __launch_bounds__(256) void xpad_kernel(const float* __restrict__ x,
                                                   unsigned short* __restrict__ xp)
{
  int i = blockIdx.x * 256 + threadIdx.x;          // grid 200 -> 51200 == 64*800
  if (i >= 64 * 800) return;
  int m = i / 800, k = i - m * 800;
  float v = (k < 784) ? x[m * 784 + k] : 0.0f;
  xp[i] = f32_to_bf16_rne(v);
}

// ---------------------------------------------------------------------------
// Pack (mu, exp(v)*sqrt2) into [k/8][n][8] float2, zero-padded in k and n.
// Layout: each 16B group holds (mu_k, mu_{k+1}, sg_k, sg_{k+1}).
__global__ __launch_bounds__(256) void pack_kernel(
    const float* __restrict__ muW0, const float* __restrict__ vW0,
    const float* __restrict__ muW1, const float* __restrict__ vW1,
    const float* __restrict__ muW2, const float* __restrict__ vW2,
    const float* __restrict__ muW3, const float* __restrict__ vW3,
    float2* __restrict__ msP0, float2* __restrict__ msP1,
    float2* __restrict__ msP2, float2* __restrict__ msP3)
{
  int b = blockIdx.x, tid = threadIdx.x;
  const float* mu; const float* v; float2* o;
  int KV, NV, osh, base;
  if (b < 1600)      { mu = muW0; v = vW0; o = msP0; KV = 784; NV = 512; osh = 9; base = 0;    }
  else if (b < 2624) { mu = muW1; v = vW1; o = msP1; KV = 512; NV = 512; osh = 9; base = 1600; }
  else if (b < 3648) { mu = muW2; v = vW2; o = msP2; KV = 512; NV = 512; osh = 9; base = 2624; }
  else               { mu = muW3; v = vW3; o = msP3; KV = 512; NV = 10;  osh = 4; base = 3648; }
  int e = (b - base) * 256 + tid;
  int k = (e & 7) | ((e >> (3 + osh)) << 3);
  int n = (e >> 3) & ((1 << osh) - 1);
  float mu_v = 0.0f, sg_v = 0.0f;
  if (k < KV && n < NV) {
    mu_v = mu[n * KV + k];
    sg_v = __expf(v[n * KV + k]) * 1.41421356237f;
  }
  // pair (e even, e+1): same n, k and k+1 (pairs never straddle KV; KV even)
  float mu_o = __shfl_xor(mu_v, 1);
  float sg_o = __shfl_xor(sg_v, 1);
  float2 r;
  if ((e & 1) == 0) { r.x = mu_v; r.y = mu_o; }
  else              { r.x = sg_o; r.y = sg_v; }
  o[e] = r;
}

// ---------------------------------------------------------------------------
// Sample all 4 bias tensors -> fp32 in ws.  b_l[s][o] = mu[o] + exp(v[o])*eps
__global__ __launch_bounds__(256) void bias_kernel(
    const float* __restrict__ mu0, const float* __restrict__ v0, float* __restrict__ o0,
    const float* __restrict__ mu1, const float* __restrict__ v1, float* __restrict__ o1,
    const float* __restrict__ mu2, const float* __restrict__ v2, float* __restrict__ o2,
    const float* __restrict__ mu3, const float* __restrict__ v3, float* __restrict__ o3,
    unsigned int k00, unsigned int k01, unsigned int k10, unsigned int k11,
    unsigned int k20, unsigned int k21, unsigned int k30, unsigned int k31)
{
  int b = blockIdx.x, tid = threadIdx.x;
  int seg = b / 300; if (seg > 3) seg = 3;
  const float* mu; const float* v; float* o; unsigned int ka, kb; int n;
  if      (seg == 0) { mu = mu0; v = v0; o = o0; ka = k00; kb = k01; n = 76800; }
  else if (seg == 1) { mu = mu1; v = v1; o = o1; ka = k10; kb = k11; n = 76800; }
  else if (seg == 2) { mu = mu2; v = v2; o = o2; ka = k20; kb = k21; n = 76800; }
  else               { mu = mu3; v = v3; o = o3; ka = k30; kb = k31; n = 1500;  }
  int e = (b - seg * 300) * 256 + tid;
  if (e >= n) return;
  int oo = (seg == 3) ? (e % 10) : (e & 511);
  float eps = 1.41421356237f * bits_to_g(tf_xor(ka, kb, (unsigned int)e));
  o[e] = __builtin_fmaf(__expf(v[oo]), eps, mu[oo]);
}

// ---------------------------------------------------------------------------
// bias3_out: initialize d_out[s][m][n] = b3s[s][n]  (150*64*10 = 96000 f32)
__global__ __launch_bounds__(256) void bias3_out(float* __restrict__ Out,
                                                 const float* __restrict__ b3s)
{
  int i = blockIdx.x * 256 + threadIdx.x;   // grid 375
  if (i >= 96000) return;
  int s = i / 640;
  int rem = i - s * 640;
  int n = rem % 10;
  Out[i] = b3s[s * 10 + n];
}

// ---------------------------------------------------------------------------
// Fused big layer (grid dim3(32,150)):
//   block = 4 waves, one 16-col n-range x all 64 m x full K; K-split across
//   waves (step st = wave + 4*i); FULLY UNROLLED over i with compile-time
//   offsets; ping-pong register prefetch pinned with sched_barrier(0);
//   LDS reduce; epilogue bias+relu, bf16 out.
// amdgpu_waves_per_eu(1,4): scheduler targets 4 waves/EU, freeing <=128 VGPR.
// mfma_f32_16x16x32_bf16: A/B frag lane holds row (lane&15), k=(lane>>4)*8+j;
// C/D lane holds col n=(lane&15), rows m=(lane>>4)*4+reg.
template<int KVALID, int KPAD, int ASTRIDE, int AROW>
__global__
__attribute__((amdgpu_flat_work_group_size(256, 256)))
__attribute__((amdgpu_waves_per_eu(1, 4)))
void layer_fused(
    const unsigned short* __restrict__ A,   // bf16 [s][64][AROW] (ASTRIDE=0: shared x)
    unsigned short* __restrict__ Out,       // bf16 [s][64][512]
    const float2* __restrict__ msP,         // [KPAD/8][512][8] (mu,mu,sg,sg pairs)
    const float* __restrict__ bS,           // [s][512]
    unsigned int k0, unsigned int k1)
{
  constexpr int NSTEPS = KPAD / 32;        // 25 (L0) or 16 (L1/L2)
  constexpr int NFULL  = NSTEPS / 4;       // uniform steps per wave: 6 or 4
  constexpr int NTAIL  = NSTEPS & 3;       // 1 (L0, wave 0 only) or 0
  constexpr int OVALID = 512, OPITCH = 512;
  const unsigned int ks2 = k0 ^ k1 ^ 0x1BD11BDAu;
  const int s    = blockIdx.y;
  const int tid  = threadIdx.x;
  const int wave = tid >> 6, lane = tid & 63;
  const int quad = lane >> 4;
  const int n16  = lane & 15;
  const int nlane = blockIdx.x * 16 + n16;

  const unsigned short* As = A + (size_t)s * ASTRIDE;
  const unsigned int idx_base = (unsigned int)s * (unsigned int)(OVALID * KVALID)
                              + (unsigned int)nlane * (unsigned int)KVALID;

  // per-wave hoisted bases: step i has k-offset kb0 + 128*i (compile-time i)
  const int kb0 = wave * 32 + quad * 8;
  const unsigned int cb_base = idx_base + (unsigned int)kb0 + k1;
  const unsigned short* aB0 = As + (size_t)(0 * 16 + n16) * AROW + kb0;
  const unsigned short* aB1 = As + (size_t)(1 * 16 + n16) * AROW + kb0;
  const unsigned short* aB2 = As + (size_t)(2 * 16 + n16) * AROW + kb0;
  const unsigned short* aB3 = As + (size_t)(3 * 16 + n16) * AROW + kb0;
  const float4* mpB = reinterpret_cast<const float4*>(
      msP + ((size_t)(kb0 >> 3) * OPITCH + nlane) * 8);

  f32x4 acc[4] = {f32x4{0,0,0,0}, f32x4{0,0,0,0}, f32x4{0,0,0,0}, f32x4{0,0,0,0}};

  auto load_step = [&](int i, bf16x8 (&af)[4], float4 (&q)[4]) {
    // A byte offset: i*256 (fits 13-bit imm for i<=15)
    af[0] = *reinterpret_cast<const bf16x8*>(aB0 + i * 128);
    af[1] = *reinterpret_cast<const bf16x8*>(aB1 + i * 128);
    af[2] = *reinterpret_cast<const bf16x8*>(aB2 + i * 128);
    af[3] = *reinterpret_cast<const bf16x8*>(aB3 + i * 128);
    const float4* mp = mpB + (size_t)i * (16 * OPITCH * 4);
    q[0] = mp[0]; q[1] = mp[1]; q[2] = mp[2]; q[3] = mp[3];
  };

  auto compute_step = [&](int i, bf16x8 (&af)[4], float4 (&q)[4]) {
    unsigned int a[8], b[8], r[8];
    const unsigned int cb = cb_base + (unsigned int)(i * 128);
    TF8_FULL(r)

    float g[8];
    #pragma unroll
    for (int j = 0; j < 8; ++j)
      g[j] = bits_to_g(r[j]);

    // q[h] = (mu_k, mu_{k+1}, sg_k, sg_{k+1}) for k = kb + 2h
    i32x4 bp;
    #pragma unroll
    for (int h = 0; h < 4; ++h) {
      float w0 = __builtin_fmaf(q[h].z, g[2 * h],     q[h].x);
      float w1 = __builtin_fmaf(q[h].w, g[2 * h + 1], q[h].y);
      bp[h] = (int)cvt_pk_bf16(w0, w1);
    }
    bf16x8 bfrag = __builtin_bit_cast(bf16x8, bp);

    #pragma unroll
    for (int mt = 0; mt < 4; ++mt)
      acc[mt] = __builtin_amdgcn_mfma_f32_16x16x32_bf16(af[mt], bfrag, acc[mt], 0, 0, 0);
  };

  // fully unrolled ping-pong: iteration i computes buffer (i&1 ? B : A),
  // prefetches step i+1 into the other buffer.
  bf16x8 afA[4], afB[4];
  float4 qA[4], qB[4];
  load_step(0, afA, qA);
  #pragma unroll
  for (int i = 0; i < NFULL; ++i) {
    const bool pf = (i + 1 < NFULL) || (wave < NTAIL);
    if (pf) {
      if ((i + 1) & 1) load_step(i + 1, afB, qB);
      else             load_step(i + 1, afA, qA);
    }
    __builtin_amdgcn_sched_barrier(0);       // prefetch stays above compute
    if (i & 1) compute_step(i, afB, qB);
    else       compute_step(i, afA, qA);
  }
  if (NTAIL > 0 && wave < NTAIL) {           // L0: wave 0 computes step 6
    __builtin_amdgcn_sched_barrier(0);
    if (NFULL & 1) compute_step(NFULL, afB, qB);
    else           compute_step(NFULL, afA, qA);
  }

  // reduce the 4 waves' partials through LDS
  __shared__ float red[4 * 16 * 64];   // 16 KB
  #pragma unroll
  for (int mt = 0; mt < 4; ++mt)
    #pragma unroll
    for (int r = 0; r < 4; ++r)
      red[(wave * 16 + mt * 4 + r) * 64 + lane] = acc[mt][r];
  __syncthreads();

  // epilogue: thread -> (m = tid>>2, n-quad = (tid&3)*4), 4 outputs each
  const int m   = tid >> 2;                    // 0..63
  const int nq  = (tid & 3) * 4;               // 0,4,8,12
  const int row = (m >> 4) * 4 + (m & 3);      // mt*4 + r
  const int col = ((m >> 2) & 3) * 16 + nq;    // quad*16 + nq

  float4 p0 = *reinterpret_cast<const float4*>(&red[(0 * 16 + row) * 64 + col]);
  float4 p1 = *reinterpret_cast<const float4*>(&red[(1 * 16 + row) * 64 + col]);
  float4 p2 = *reinterpret_cast<const float4*>(&red[(2 * 16 + row) * 64 + col]);
  float4 p3 = *reinterpret_cast<const float4*>(&red[(3 * 16 + row) * 64 + col]);
  float v0 = (p0.x + p1.x) + (p2.x + p3.x);
  float v1 = (p0.y + p1.y) + (p2.y + p3.y);
  float v2 = (p0.z + p1.z) + (p2.z + p3.z);
  float v3 = (p0.w + p1.w) + (p2.w + p3.w);

  const float4 b4 = *reinterpret_cast<const float4*>(
      &bS[s * OVALID + blockIdx.x * 16 + nq]);
  float o0 = fmaxf(v0 + b4.x, 0.0f), o1 = fmaxf(v1 + b4.y, 0.0f);
  float o2 = fmaxf(v2 + b4.z, 0.0f), o3 = fmaxf(v3 + b4.w, 0.0f);
  uint2 stv;
  stv.x = cvt_pk_bf16(o0, o1);
  stv.y = cvt_pk_bf16(o2, o3);
  *reinterpret_cast<uint2*>(
      Out + ((size_t)s * 64 + m) * OPITCH + blockIdx.x * 16 + nq) = stv;
}

// ---------------------------------------------------------------------------
// layer3_atomic: last layer with K-split ACROSS BLOCKS. grid dim3(4,150):
// block bx covers k-steps [bx*4, bx*4+4), one step per wave (RNG exactly once
// per (s,n,k)). 4-wave LDS reduce, then atomicAdd f32 partials onto d_out
// (pre-initialized with bias by bias3_out).
__global__ __launch_bounds__(256) void layer3_atomic(
    const unsigned short* __restrict__ A,   // bf16 [s][64][512]
    float* __restrict__ Out,                // f32 [s][64][10], bias pre-added
    const float2* __restrict__ msP,         // [64][16][8] (mu,mu,sg,sg), n-padded
    unsigned int k0, unsigned int k1)
{
  const unsigned int ks2 = k0 ^ k1 ^ 0x1BD11BDAu;
  const int s    = blockIdx.y;
  const int tid  = threadIdx.x;
  const int wave = tid >> 6, lane = tid & 63;
  const int quad = lane >> 4;
  const int n    = lane & 15;

  const unsigned short* As = A + (size_t)s * (64 * 512);
  const int st = blockIdx.x * 4 + wave;      // 0..15
  const int kb = st * 32 + quad * 8;
  const unsigned int idx_base = (unsigned int)s * 5120u + (unsigned int)n * 512u;

  // mu/sigma (padded n in [10,16) have mu=sigma=0 -> weight 0)
  const float4* mp = reinterpret_cast<const float4*>(
      msP + ((size_t)(kb >> 3) * 16 + n) * 8);
  float4 q[4];
  #pragma unroll
  for (int h = 0; h < 4; ++h) q[h] = mp[h];

  unsigned int a[8], b[8], r[8];
  const unsigned int cb = idx_base + (unsigned int)kb + k1;
  TF8_FULL(r)

  float g[8];
  #pragma unroll
  for (int j = 0; j < 8; ++j)
    g[j] = bits_to_g(r[j]);

  i32x4 bp;
  #pragma unroll
  for (int h = 0; h < 4; ++h) {
    float w0 = __builtin_fmaf(q[h].z, g[2 * h],     q[h].x);
    float w1 = __builtin_fmaf(q[h].w, g[2 * h + 1], q[h].y);
    bp[h] = (int)cvt_pk_bf16(w0, w1);
  }
  bf16x8 bfrag = __builtin_bit_cast(bf16x8, bp);

  f32x4 acc[4] = {f32x4{0,0,0,0}, f32x4{0,0,0,0}, f32x4{0,0,0,0}, f32x4{0,0,0,0}};
  #pragma unroll
  for (int mt = 0; mt < 4; ++mt) {
    bf16x8 afrag = *reinterpret_cast<const bf16x8*>(
        As + (size_t)(mt * 16 + n) * 512 + kb);
    acc[mt] = __builtin_amdgcn_mfma_f32_16x16x32_bf16(afrag, bfrag, acc[mt], 0, 0, 0);
  }

  __shared__ float red[4 * 16 * 64];   // 16 KB
  #pragma unroll
  for (int mt = 0; mt < 4; ++mt)
    #pragma unroll
    for (int rr = 0; rr < 4; ++rr)
      red[(wave * 16 + mt * 4 + rr) * 64 + lane] = acc[mt][rr];
  __syncthreads();

  const int m   = tid >> 2;                    // 0..63
  const int nq  = (tid & 3) * 4;               // 0,4,8,12
  const int row = (m >> 4) * 4 + (m & 3);
  const int col = ((m >> 2) & 3) * 16 + nq;

  float4 p0 = *reinterpret_cast<const float4*>(&red[(0 * 16 + row) * 64 + col]);
  float4 p1 = *reinterpret_cast<const float4*>(&red[(1 * 16 + row) * 64 + col]);
  float4 p2 = *reinterpret_cast<const float4*>(&red[(2 * 16 + row) * 64 + col]);
  float4 p3 = *reinterpret_cast<const float4*>(&red[(3 * 16 + row) * 64 + col]);
  float vv[4];
  vv[0] = (p0.x + p1.x) + (p2.x + p3.x);
  vv[1] = (p0.y + p1.y) + (p2.y + p3.y);
  vv[2] = (p0.z + p1.z) + (p2.z + p3.z);
  vv[3] = (p0.w + p1.w) + (p2.w + p3.w);

  #pragma unroll
  for (int jj = 0; jj < 4; ++jj) {
    int nn = nq + jj;
    if (nn < 10)
      atomicAdd(&Out[((size_t)s * 64 + m) * 10 + nn], vv[jj]);
  }
}

// ---------------------------------------------------------------------------
// Host-side threefry for jax.random.split(key(1), 8)
static void tf_host(unsigned int k0, unsigned int k1, unsigned int c0, unsigned int c1,
                    unsigned int* o0, unsigned int* o1)
{
  const unsigned int ks2 = k0 ^ k1 ^ 0x1BD11BDAu;
  unsigned int x0 = c0 + k0, x1 = c1 + k1;
  TF_R(13) TF_R(15) TF_R(26) TF_R(6)
  x0 += k1;  x1 += ks2 + 1u;
  TF_R(17) TF_R(29) TF_R(16) TF_R(24)
  x0 += ks2; x1 += k0 + 2u;
  TF_R(13) TF_R(15) TF_R(26) TF_R(6)
  x0 += k0;  x1 += k1 + 3u;
  TF_R(17) TF_R(29) TF_R(16) TF_R(24)
  x0 += k1;  x1 += ks2 + 4u;
  TF_R(13) TF_R(15) TF_R(26) TF_R(6)
  x0 += ks2; x1 += k0 + 5u;
  *o0 = x0; *o1 = x1;
}

extern "C" void kernel_launch(void* const* d_in, const int* in_sizes, int n_in,
                              void* d_out, int out_size, void* d_ws, size_t ws_size,
                              hipStream_t stream)
{
  (void)in_sizes; (void)n_in; (void)out_size; (void)ws_size;

  const float* x    = (const float*)d_in[0];
  const float* muW0 = (const float*)d_in[1];
  const float* mub0 = (const float*)d_in[2];
  const float* muW1 = (const float*)d_in[3];
  const float* mub1 = (const float*)d_in[4];
  const float* muW2 = (const float*)d_in[5];
  const float* mub2 = (const float*)d_in[6];
  const float* muW3 = (const float*)d_in[7];
  const float* mub3 = (const float*)d_in[8];
  const float* vW0  = (const float*)d_in[9];
  const float* vb0  = (const float*)d_in[10];
  const float* vW1  = (const float*)d_in[11];
  const float* vb1  = (const float*)d_in[12];
  const float* vW2  = (const float*)d_in[13];
  const float* vb2  = (const float*)d_in[14];
  const float* vW3  = (const float*)d_in[15];
  const float* vb3  = (const float*)d_in[16];

  // keys: split(key(1), 8) -> ks[0]:W0 ks[1]:b0 ks[2]:W1 ks[3]:b1 ...
  unsigned int key[8][2];
  for (unsigned int i = 0; i < 8; ++i)
    tf_host(0u, 1u, 0u, i, &key[i][0], &key[i][1]);

  // ws layout (~25.0 MB; hB aliases msP0 — msP0 is dead once L0 completes)
  char* ws = (char*)d_ws;
  unsigned short* xp = (unsigned short*)(ws);                 // 64*800*2 = 102,400
  unsigned short* hA = (unsigned short*)(ws + 106496);        // 150*64*512*2 = 9,830,400
  float* b0s  = (float*)(ws + 9936896);                       // 150*512*4 = 307,200
  float* b1s  = (float*)(ws + 10244096);
  float* b2s  = (float*)(ws + 10551296);
  float* b3s  = (float*)(ws + 10858496);                      // 150*10*4 (pad 8,192)
  float2* msP1 = (float2*)(ws + 10866688);                    // 2,097,152
  float2* msP2 = (float2*)(ws + 12963840);                    // 2,097,152
  float2* msP3 = (float2*)(ws + 15060992);                    // 65,536
  float2* msP0 = (float2*)(ws + 15126528);                    // 3,276,800
  unsigned short* hB = (unsigned short*)(ws + 15126528);      // aliases msP0

  xpad_kernel<<<200, 256, 0, stream>>>(x, xp);
  pack_kernel<<<3680, 256, 0, stream>>>(muW0, vW0, muW1, vW1, muW2, vW2, muW3, vW3,
                                        msP0, msP1, msP2, msP3);
  bias_kernel<<<906, 256, 0, stream>>>(mub0, vb0, b0s, mub1, vb1, b1s,
                                       mub2, vb2, b2s, mub3, vb3, b3s,
                                       key[1][0], key[1][1], key[3][0], key[3][1],
                                       key[5][0], key[5][1], key[7][0], key[7][1]);
  bias3_out<<<375, 256, 0, stream>>>((float*)d_out, b3s);

  // L0: x(64,784 pad 800) -> hA ; L1: hA -> hB (kills msP0) ; L2: hB -> hA ;
  // L3: hA -> out (K-split atomic, RNG x1)
  layer_fused<784, 800, 0,     800><<<dim3(32, 150), 256, 0, stream>>>(
      xp, hA, msP0, b0s, key[0][0], key[0][1]);
  layer_fused<512, 512, 32768, 512><<<dim3(32, 150), 256, 0, stream>>>(
      hA, hB, msP1, b1s, key[2][0], key[2][1]);
  layer_fused<512, 512, 32768, 512><<<dim3(32, 150), 256, 0, stream>>>(
      hB, hA, msP2, b2s, key[4][0], key[4][1]);
  layer3_atomic<<<dim3(4, 150), 256, 0, stream>>>(
      hA, (float*)d_out, msP3, key[6][0], key[6][1]);
}